// Round 5
// baseline (303.388 us; speedup 1.0000x reference)
//
#include <hip/hip_runtime.h>
#include <math.h>

typedef unsigned short u16;
typedef __attribute__((ext_vector_type(8))) short short8;   // 8 bf16 = 4 VGPRs
typedef __attribute__((ext_vector_type(4))) float floatx4;  // MFMA 16x16 C/D

// fp32 -> bf16 round-to-nearest-even
__device__ __forceinline__ u16 f2bf(float f) {
  union { float f; unsigned u; } v; v.f = f;
  unsigned r = (v.u + 0x7FFFu + ((v.u >> 16) & 1u)) >> 16;
  return (u16)r;
}

// async global->LDS, 16B per lane; LDS dest must be wave-uniform base + lane*16
#define GLD16(gp, lp) __builtin_amdgcn_global_load_lds(                      \
    (__attribute__((address_space(1))) void*)(gp),                           \
    (__attribute__((address_space(3))) void*)(lp), 16, 0, 0)

// ---------------------------------------------------------------------------
// f32 -> bf16 conversion: 5 tensors of 4194304 elements each, contiguous dst.
// ---------------------------------------------------------------------------
__global__ __launch_bounds__(256) void cvt_all(
    const float* __restrict__ H, const float* __restrict__ Wq,
    const float* __restrict__ Wk, const float* __restrict__ Wv,
    const float* __restrict__ Wo, u16* __restrict__ dst) {
  const float* srcs[5] = {H, Wq, Wk, Wv, Wo};
  const int sel = blockIdx.y;
  const float* s = srcs[sel];
  u16* d = dst + (size_t)sel * 4194304;
  const int idx = (blockIdx.x * 256 + threadIdx.x) * 4;
  const float4 v = *(const float4*)(s + idx);
  ushort4 o;
  o.x = f2bf(v.x); o.y = f2bf(v.y); o.z = f2bf(v.z); o.w = f2bf(v.w);
  *(ushort4*)(d + idx) = o;
}

// ---------------------------------------------------------------------------
// GEMM core: C[m,n] = sum_{k in [k_lo,k_hi)} A[m,k] * B[n,k]  (B^T layout)
// 128x128 tile, BK=64, 4 waves each computing 64x64 (4x4 MFMA tiles).
// mode 0: f32 atomic-accumulate into C row-major [2048,2048] (split-K)
// mode 1: head-split bf16   [bh,1024,64]   (Q,K; cscale folds 1/sqrt(D) into Q)
// mode 2: head-split-T bf16 [bh,64,1024]   (V^T)
// ---------------------------------------------------------------------------
__device__ __forceinline__ void gemm_core(const u16* __restrict__ A,
                                          const u16* __restrict__ B,
                                          u16* __restrict__ Cb,
                                          float* __restrict__ Cf,
                                          int M0, int N0, int mode, float cscale,
                                          int k_lo, int k_hi,
                                          u16* lA, u16* lB) {
  const int tid = threadIdx.x;
  const int lane = tid & 63;
  const int wave = tid >> 6;
  const int lq = lane & 15, quad = lane >> 4;
  const int wm = wave & 1, wn = wave >> 1;

  floatx4 acc[4][4];
#pragma unroll
  for (int i = 0; i < 4; ++i)
#pragma unroll
    for (int j = 0; j < 4; ++j) acc[i][j] = (floatx4)0.f;

  const int srow = tid >> 3;
  const int scol = (tid & 7) << 3;

  for (int k0 = k_lo; k0 < k_hi; k0 += 64) {
    __syncthreads();
#pragma unroll
    for (int r = 0; r < 4; ++r) {
      const int row = r * 32 + srow;
      const int flat = row * 64 + scol;
      GLD16(A + (size_t)(M0 + row) * 2048 + k0 + scol, lA + flat);
      GLD16(B + (size_t)(N0 + row) * 2048 + k0 + scol, lB + flat);
    }
    __syncthreads();
#pragma unroll
    for (int ks = 0; ks < 64; ks += 32) {
      short8 af[4], bf[4];
#pragma unroll
      for (int t = 0; t < 4; ++t)
        af[t] = *(const short8*)&lA[(wm * 64 + t * 16 + lq) * 64 + ks + quad * 8];
#pragma unroll
      for (int t = 0; t < 4; ++t)
        bf[t] = *(const short8*)&lB[(wn * 64 + t * 16 + lq) * 64 + ks + quad * 8];
#pragma unroll
      for (int i = 0; i < 4; ++i)
#pragma unroll
        for (int j = 0; j < 4; ++j)
          acc[i][j] = __builtin_amdgcn_mfma_f32_16x16x32_bf16(af[i], bf[j], acc[i][j], 0, 0, 0);
    }
  }

  // epilogue: C/D layout col=lane&15, row=quad*4+reg
#pragma unroll
  for (int i = 0; i < 4; ++i)
#pragma unroll
    for (int j = 0; j < 4; ++j)
#pragma unroll
      for (int r = 0; r < 4; ++r) {
        const int m = M0 + wm * 64 + i * 16 + quad * 4 + r;
        const int n = N0 + wn * 64 + j * 16 + lq;
        if (mode == 0) {
          unsafeAtomicAdd(&Cf[(size_t)m * 2048 + n], acc[i][j][r]);  // global_atomic_add_f32
        } else {
          const int bh = ((m >> 10) << 5) | (n >> 6);  // b*32 + head
          size_t addr;
          if (mode == 1) addr = ((size_t)bh * 1024 + (m & 1023)) * 64 + (n & 63);
          else           addr = ((size_t)bh * 64 + (n & 63)) * 1024 + (m & 1023);
          Cb[addr] = f2bf(acc[i][j][r] * cscale);
        }
      }
}

__global__ __launch_bounds__(256, 3) void gemm_qkv(
    const u16* __restrict__ H,
    const u16* __restrict__ Wq, const u16* __restrict__ Wk, const u16* __restrict__ Wv,
    u16* __restrict__ q, u16* __restrict__ k, u16* __restrict__ vt) {
  __shared__ __align__(16) u16 lA[128 * 64];
  __shared__ __align__(16) u16 lB[128 * 64];
  const int M0 = blockIdx.x * 128;
  const int sel = blockIdx.y >> 4;        // 0:Q 1:K 2:V
  const int N0 = (blockIdx.y & 15) * 128;
  const u16* B = (sel == 0) ? Wq : (sel == 1) ? Wk : Wv;
  u16* C = (sel == 0) ? q : (sel == 1) ? k : vt;
  gemm_core(H, B, C, nullptr, M0, N0, (sel == 2) ? 2 : 1,
            (sel == 0) ? 0.125f : 1.f, 0, 2048, lA, lB);
}

__global__ __launch_bounds__(256, 3) void gemm_out(
    const u16* __restrict__ A, const u16* __restrict__ W, float* __restrict__ C) {
  __shared__ __align__(16) u16 lA[128 * 64];
  __shared__ __align__(16) u16 lB[128 * 64];
  const int kz = blockIdx.z;   // split-K: 2 halves, atomic f32 accumulate
  gemm_core(A, W, nullptr, C, blockIdx.x * 128, blockIdx.y * 128, 0, 1.f,
            kz * 1024, (kz + 1) * 1024, lA, lB);
}

// ---------------------------------------------------------------------------
// Stick-breaking attention, multiplicative form, transposed z:
//   p = sigmoid(z), att[i,j] = p(i,j) * prod_{j<k<i} (1 - p(i,k))
// z' = K·Q^T via MFMA -> C-layout: lane holds query=lq, keys=16c+quad*4+r.
// Suffix product over keys: 3 in-register mults + 2-step cross-quad shuffle.
// P written [query][key] (B-frag layout), PV = MFMA(A=Vt, B=P') -> O^T,
// transposed back through LDS for coalesced stores.
// One masked (diagonal) 64-key tile, then unmasked full tiles downward.
// ---------------------------------------------------------------------------
#define PSTR 72  // P slab row stride in u16 (64 + 8 pad; rows 144B, 16B-aligned)

template <bool MASKED>
__device__ __forceinline__ void sba_tile(
    int j0, int q0, int lq, int quad,
    const u16* __restrict__ kb0, const u16* __restrict__ vb, u16* pw,
    const short8& qf0, const short8& qf1,
    floatx4 (&o)[4], float& carry) {
  // K A-frags: A[m=key 16c+lq][k=d chunk]
  short8 kf0[4], kf1[4];
#pragma unroll
  for (int c = 0; c < 4; ++c) {
    const u16* kr = &kb0[(size_t)(j0 + 16 * c + lq) * 64 + quad * 8];
    kf0[c] = *(const short8*)kr;
    kf1[c] = *(const short8*)(kr + 32);
  }
  floatx4 zc[4];
#pragma unroll
  for (int c = 0; c < 4; ++c) {
    floatx4 z = (floatx4)0.f;
    z = __builtin_amdgcn_mfma_f32_16x16x32_bf16(kf0[c], qf0, z, 0, 0, 0);
    z = __builtin_amdgcn_mfma_f32_16x16x32_bf16(kf1[c], qf1, z, 0, 0, 0);
    zc[c] = z;
  }
  // V A-frags for PV (issued early; used ~400 cycles later)
  short8 vfA[4], vfB[4];
#pragma unroll
  for (int tt = 0; tt < 4; ++tt) {
    const u16* vr = &vb[(size_t)(tt * 16 + lq) * 1024 + j0 + quad * 8];
    vfA[tt] = *(const short8*)vr;
    vfB[tt] = *(const short8*)(vr + 32);
  }

  float cur = carry;
#pragma unroll
  for (int c = 3; c >= 0; --c) {
    float p[4], g[4];
#pragma unroll
    for (int r = 0; r < 4; ++r) {
      const float z = zc[c][r];
      const float e = __expf(-z);
      float pp = __builtin_amdgcn_rcpf(1.f + e);   // sigmoid
      float gg = e * pp;                            // 1 - sigmoid
      if (MASKED) {
        const bool valid = (j0 + 16 * c + quad * 4 + r) < (q0 + lq);
        gg = valid ? gg : 1.f;
        pp = valid ? pp : 0.f;
      }
      p[r] = pp; g[r] = gg;
    }
    // in-register exclusive suffix over r (keys quad*4+r), then cross-quad
    const float er2 = g[3];
    const float er1 = er2 * g[2];
    const float er0 = er1 * g[1];
    const float qt  = er0 * g[0];     // product of this quad's 4 keys
    float x = qt;
    float v = __shfl_down(x, 16); x *= (quad < 3) ? v : 1.f;
    v = __shfl_down(x, 32);       x *= (quad < 2) ? v : 1.f;   // inclusive quad-suffix
    float Qs = __shfl_down(x, 16); Qs = (quad < 3) ? Qs : 1.f; // exclusive quad-suffix
    const float tot = __shfl(x, lq);  // full 16-key product (from quad 0, same query)
    const float QF = Qs * cur;
    ushort4 pk;
    pk.x = f2bf(p[0] * (er0 * QF));
    pk.y = f2bf(p[1] * (er1 * QF));
    pk.z = f2bf(p[2] * (er2 * QF));
    pk.w = f2bf(p[3] * QF);
    *(ushort4*)&pw[lq * PSTR + c * 16 + quad * 4] = pk;  // [query][key] row-major
    cur *= tot;
  }
  carry = cur;
  __asm__ volatile("s_waitcnt lgkmcnt(0)" ::: "memory");  // P visible to own wave
  const short8 pA = *(const short8*)&pw[lq * PSTR + quad * 8];       // keys j0+0..31
  const short8 pB = *(const short8*)&pw[lq * PSTR + 32 + quad * 8];  // keys j0+32..63
#pragma unroll
  for (int tt = 0; tt < 4; ++tt) {
    o[tt] = __builtin_amdgcn_mfma_f32_16x16x32_bf16(vfA[tt], pA, o[tt], 0, 0, 0);
    o[tt] = __builtin_amdgcn_mfma_f32_16x16x32_bf16(vfB[tt], pB, o[tt], 0, 0, 0);
  }
  // DS is in-order per wave: next tile's ds_write cannot pass the reads above.
}

__global__ __launch_bounds__(256, 4) void sba_attn(
    const u16* __restrict__ Q, const u16* __restrict__ Km,
    const u16* __restrict__ Vt, u16* __restrict__ AO) {
  __shared__ __align__(16) u16 lP[4][16 * PSTR];
  const int tid = threadIdx.x;
  const int lane = tid & 63;
  const int wave = tid >> 6;
  const int lq = lane & 15, quad = lane >> 4;
  // XCD-affinity swizzle: all 16 blocks of one head land on one XCD (%8 heuristic)
  const int blk = blockIdx.x;
  const int xcd = blk & 7, y = blk >> 3;
  const int bh = xcd + 8 * (y >> 4);
  const int u = (y & 15) * 4 + wave;
  const int t = (u & 1) ? (63 - (u >> 1)) : (u >> 1);  // balance: pair t with 63-t
  const int q0 = t << 4;

  // Q B-frags (pre-scaled by 1/8 in gemm_qkv): B[n=query=lq][k=d]
  const u16* qb = Q + ((size_t)bh * 1024 + q0) * 64;
  const short8 qf0 = *(const short8*)&qb[lq * 64 + quad * 8];
  const short8 qf1 = *(const short8*)&qb[lq * 64 + 32 + quad * 8];

  const u16* kb0 = Km + (size_t)bh * 65536;
  const u16* vb  = Vt + (size_t)bh * 65536;

  floatx4 o[4];
#pragma unroll
  for (int tt = 0; tt < 4; ++tt) o[tt] = (floatx4)0.f;
  float carry = 1.f;
  u16* pw = &lP[wave][0];

  const int j0d = q0 & ~63;  // 64-aligned diagonal tile
  sba_tile<true>(j0d, q0, lq, quad, kb0, vb, pw, qf0, qf1, o, carry);
  for (int j0 = j0d - 64; j0 >= 0; j0 -= 64)
    sba_tile<false>(j0, q0, lq, quad, kb0, vb, pw, qf0, qf1, o, carry);

  // O^T (d=tt*16+quad*4+r, query=lq) -> LDS [query][d] -> coalesced 16B stores
#pragma unroll
  for (int tt = 0; tt < 4; ++tt) {
    ushort4 pk;
    pk.x = f2bf(o[tt][0]); pk.y = f2bf(o[tt][1]);
    pk.z = f2bf(o[tt][2]); pk.w = f2bf(o[tt][3]);
    *(ushort4*)&pw[lq * PSTR + tt * 16 + quad * 4] = pk;
  }
  __asm__ volatile("s_waitcnt lgkmcnt(0)" ::: "memory");
  const int b = bh >> 5, hd = bh & 31;
#pragma unroll
  for (int ps = 0; ps < 2; ++ps) {
    const int row = lane >> 2;
    const int colu = ((lane & 3) + 4 * ps) * 8;
    const short8 val = *(const short8*)&pw[row * PSTR + colu];
    *(short8*)&AO[((size_t)b * 1024 + q0 + row) * 2048 + hd * 64 + colu] = val;
  }
}

extern "C" void kernel_launch(void* const* d_in, const int* in_sizes, int n_in,
                              void* d_out, int out_size, void* d_ws, size_t ws_size,
                              hipStream_t stream) {
  const float* H  = (const float*)d_in[0];
  const float* Wq = (const float*)d_in[1];
  const float* Wk = (const float*)d_in[2];
  const float* Wv = (const float*)d_in[3];
  const float* Wo = (const float*)d_in[4];

  u16* ws = (u16*)d_ws;
  u16* Hb  = ws;                  // [2048,2048] 8MB  (reused as ao after gemm_qkv)
  u16* Wqb = ws + 1 * 4194304;
  u16* Wkb = ws + 2 * 4194304;
  u16* Wvb = ws + 3 * 4194304;
  u16* Wob = ws + 4 * 4194304;
  u16* q   = ws + 5 * 4194304;    // [64,1024,64], pre-scaled by 1/8
  u16* k   = ws + 6 * 4194304;
  u16* vt  = ws + 7 * 4194304;    // [64,64,1024]
  u16* ao  = Hb;                  // alias: H consumed by gemm_qkv before sba_attn writes

  dim3 gc(4096, 5);
  cvt_all<<<gc, 256, 0, stream>>>(H, Wq, Wk, Wv, Wo, ws);

  dim3 gq(16, 48);
  gemm_qkv<<<gq, 256, 0, stream>>>(Hb, Wqb, Wkb, Wvb, q, k, vt);
  sba_attn<<<1024, 256, 0, stream>>>(q, k, vt, ao);

  // zero d_out for split-K atomic accumulation (graph-legal memset node)
  hipMemsetAsync(d_out, 0, (size_t)out_size * sizeof(float), stream);
  dim3 go(16, 16, 2);
  gemm_out<<<go, 256, 0, stream>>>(ao, Wob, (float*)d_out);
}

// Round 6
// 275.498 us; speedup vs baseline: 1.1012x; 1.1012x over previous
//
#include <hip/hip_runtime.h>
#include <math.h>

typedef unsigned short u16;
typedef __attribute__((ext_vector_type(8))) short short8;   // 8 bf16 = 4 VGPRs
typedef __attribute__((ext_vector_type(4))) float floatx4;  // MFMA 16x16 C/D

// fp32 -> bf16 round-to-nearest-even
__device__ __forceinline__ u16 f2bf(float f) {
  union { float f; unsigned u; } v; v.f = f;
  unsigned r = (v.u + 0x7FFFu + ((v.u >> 16) & 1u)) >> 16;
  return (u16)r;
}

// async global->LDS, 16B per lane; LDS dest must be wave-uniform base + lane*16
#define GLD16(gp, lp) __builtin_amdgcn_global_load_lds(                      \
    (__attribute__((address_space(1))) void*)(gp),                           \
    (__attribute__((address_space(3))) void*)(lp), 16, 0, 0)

// ---------------------------------------------------------------------------
// f32 -> bf16 conversion: 5 tensors of 4194304 elements each, contiguous dst.
// ---------------------------------------------------------------------------
__global__ __launch_bounds__(256) void cvt_all(
    const float* __restrict__ H, const float* __restrict__ Wq,
    const float* __restrict__ Wk, const float* __restrict__ Wv,
    const float* __restrict__ Wo, u16* __restrict__ dst) {
  const float* srcs[5] = {H, Wq, Wk, Wv, Wo};
  const int sel = blockIdx.y;
  const float* s = srcs[sel];
  u16* d = dst + (size_t)sel * 4194304;
  const int idx = (blockIdx.x * 256 + threadIdx.x) * 4;
  const float4 v = *(const float4*)(s + idx);
  ushort4 o;
  o.x = f2bf(v.x); o.y = f2bf(v.y); o.z = f2bf(v.z); o.w = f2bf(v.w);
  *(ushort4*)(d + idx) = o;
}

// ---------------------------------------------------------------------------
// GEMM core: C[m,n] = sum_k A[m,k] * B[n,k]  (B^T layout, all dims 2048)
// 128x128 tile, BK=64, 4 waves each computing 64x64 (4x4 MFMA tiles).
//
// LDS bank-conflict fix (R5: 18.9M conflict-cycles = 39% of kernel): row
// stride is 64 u16 = 128 B = 32 banks, so all rows start at bank 0 and the
// 16 lq-lanes of a fragment read were 16-way conflicted. We XOR-swizzle the
// COLUMN CHUNK per row: LDS slot (row, cc) holds global chunk cc^(row&7).
// Staging keeps the flat contiguous LDS dest (GLD16 constraint); only the
// per-lane GLOBAL address is permuted (same 128B line set -> still coalesced).
// Fragment reads use chunk c^(row&7): bank start 4*((c)^(lq&7)) sweeps all 8
// bank groups across lq -> 2-way only (free, m136).
//
// mode 0: C row-major fp32 [2048,2048]  (final output)
// mode 1: head-split bf16   [bh,1024,64]   (Q,K; cscale folds 1/sqrt(D) into Q)
// mode 2: head-split-T bf16 [bh,64,1024]   (V^T)
// ---------------------------------------------------------------------------
__device__ __forceinline__ void gemm_core(const u16* __restrict__ A,
                                          const u16* __restrict__ B,
                                          u16* __restrict__ Cb,
                                          float* __restrict__ Cf,
                                          int M0, int N0, int mode, float cscale,
                                          u16* lA, u16* lB) {
  const int tid = threadIdx.x;
  const int lane = tid & 63;
  const int wave = tid >> 6;
  const int lq = lane & 15, quad = lane >> 4;
  const int wm = wave & 1, wn = wave >> 1;

  floatx4 acc[4][4];
#pragma unroll
  for (int i = 0; i < 4; ++i)
#pragma unroll
    for (int j = 0; j < 4; ++j) acc[i][j] = (floatx4)0.f;

  const int srow = tid >> 3;        // 0..31
  const int cc = tid & 7;           // column chunk 0..7

  for (int k0 = 0; k0 < 2048; k0 += 64) {
    __syncthreads();
#pragma unroll
    for (int r = 0; r < 4; ++r) {
      const int row = r * 32 + srow;
      const int gcol = ((cc ^ (row & 7)) << 3);   // swizzled global chunk
      const int flat = row * 64 + (cc << 3);      // contiguous LDS dest
      GLD16(A + (size_t)(M0 + row) * 2048 + k0 + gcol, lA + flat);
      GLD16(B + (size_t)(N0 + row) * 2048 + k0 + gcol, lB + flat);
    }
    __syncthreads();
    const int sw = lq & 7;
#pragma unroll
    for (int ks8 = 0; ks8 < 8; ks8 += 4) {        // ks = ks8*8 in {0,32}
      short8 af[4], bf[4];
#pragma unroll
      for (int t = 0; t < 4; ++t)
        af[t] = *(const short8*)&lA[(wm * 64 + t * 16 + lq) * 64 + (((quad + ks8) ^ sw) << 3)];
#pragma unroll
      for (int t = 0; t < 4; ++t)
        bf[t] = *(const short8*)&lB[(wn * 64 + t * 16 + lq) * 64 + (((quad + ks8) ^ sw) << 3)];
#pragma unroll
      for (int i = 0; i < 4; ++i)
#pragma unroll
        for (int j = 0; j < 4; ++j)
          acc[i][j] = __builtin_amdgcn_mfma_f32_16x16x32_bf16(af[i], bf[j], acc[i][j], 0, 0, 0);
    }
  }

  // epilogue: C/D layout col=lane&15, row=quad*4+reg
#pragma unroll
  for (int i = 0; i < 4; ++i)
#pragma unroll
    for (int j = 0; j < 4; ++j)
#pragma unroll
      for (int r = 0; r < 4; ++r) {
        const int m = M0 + wm * 64 + i * 16 + quad * 4 + r;
        const int n = N0 + wn * 64 + j * 16 + lq;
        if (mode == 0) {
          Cf[(size_t)m * 2048 + n] = acc[i][j][r];
        } else {
          const int bh = ((m >> 10) << 5) | (n >> 6);  // b*32 + head
          size_t addr;
          if (mode == 1) addr = ((size_t)bh * 1024 + (m & 1023)) * 64 + (n & 63);
          else           addr = ((size_t)bh * 64 + (n & 63)) * 1024 + (m & 1023);
          Cb[addr] = f2bf(acc[i][j][r] * cscale);
        }
      }
}

__global__ __launch_bounds__(256, 3) void gemm_qkv(
    const u16* __restrict__ H,
    const u16* __restrict__ Wq, const u16* __restrict__ Wk, const u16* __restrict__ Wv,
    u16* __restrict__ q, u16* __restrict__ k, u16* __restrict__ vt) {
  __shared__ __align__(16) u16 lA[128 * 64];
  __shared__ __align__(16) u16 lB[128 * 64];
  const int M0 = blockIdx.x * 128;
  const int sel = blockIdx.y >> 4;        // 0:Q 1:K 2:V
  const int N0 = (blockIdx.y & 15) * 128;
  const u16* B = (sel == 0) ? Wq : (sel == 1) ? Wk : Wv;
  u16* C = (sel == 0) ? q : (sel == 1) ? k : vt;
  gemm_core(H, B, C, nullptr, M0, N0, (sel == 2) ? 2 : 1,
            (sel == 0) ? 0.125f : 1.f, lA, lB);
}

__global__ __launch_bounds__(256, 3) void gemm_out(
    const u16* __restrict__ A, const u16* __restrict__ W, float* __restrict__ C) {
  __shared__ __align__(16) u16 lA[128 * 64];
  __shared__ __align__(16) u16 lB[128 * 64];
  gemm_core(A, W, nullptr, C, blockIdx.x * 128, blockIdx.y * 128, 0, 1.f, lA, lB);
}

// ---------------------------------------------------------------------------
// Stick-breaking attention, multiplicative form, transposed z:
//   p = sigmoid(z), att[i,j] = p(i,j) * prod_{j<k<i} (1 - p(i,k))
// z' = K·Q^T via MFMA -> C-layout: lane holds query=lq, keys=16c+quad*4+r.
// Suffix product over keys: 3 in-register mults + 2-step cross-quad shuffle.
// P written [query][key] (B-frag layout), PV = MFMA(A=Vt, B=P') -> O^T,
// transposed back through LDS for coalesced stores.
// One masked (diagonal) 64-key tile, then unmasked full tiles downward.
// ---------------------------------------------------------------------------
#define PSTR 72  // P slab row stride in u16 (64 + 8 pad; rows 144B, 16B-aligned)

template <bool MASKED>
__device__ __forceinline__ void sba_tile(
    int j0, int q0, int lq, int quad,
    const u16* __restrict__ kb0, const u16* __restrict__ vb, u16* pw,
    const short8& qf0, const short8& qf1,
    floatx4 (&o)[4], float& carry) {
  // K A-frags: A[m=key 16c+lq][k=d chunk]
  short8 kf0[4], kf1[4];
#pragma unroll
  for (int c = 0; c < 4; ++c) {
    const u16* kr = &kb0[(size_t)(j0 + 16 * c + lq) * 64 + quad * 8];
    kf0[c] = *(const short8*)kr;
    kf1[c] = *(const short8*)(kr + 32);
  }
  floatx4 zc[4];
#pragma unroll
  for (int c = 0; c < 4; ++c) {
    floatx4 z = (floatx4)0.f;
    z = __builtin_amdgcn_mfma_f32_16x16x32_bf16(kf0[c], qf0, z, 0, 0, 0);
    z = __builtin_amdgcn_mfma_f32_16x16x32_bf16(kf1[c], qf1, z, 0, 0, 0);
    zc[c] = z;
  }
  // V A-frags for PV (issued early; used ~400 cycles later)
  short8 vfA[4], vfB[4];
#pragma unroll
  for (int tt = 0; tt < 4; ++tt) {
    const u16* vr = &vb[(size_t)(tt * 16 + lq) * 1024 + j0 + quad * 8];
    vfA[tt] = *(const short8*)vr;
    vfB[tt] = *(const short8*)(vr + 32);
  }

  float cur = carry;
#pragma unroll
  for (int c = 3; c >= 0; --c) {
    float p[4], g[4];
#pragma unroll
    for (int r = 0; r < 4; ++r) {
      const float z = zc[c][r];
      const float e = __expf(-z);
      float pp = __builtin_amdgcn_rcpf(1.f + e);   // sigmoid
      float gg = e * pp;                            // 1 - sigmoid
      if (MASKED) {
        const bool valid = (j0 + 16 * c + quad * 4 + r) < (q0 + lq);
        gg = valid ? gg : 1.f;
        pp = valid ? pp : 0.f;
      }
      p[r] = pp; g[r] = gg;
    }
    // in-register exclusive suffix over r (keys quad*4+r), then cross-quad
    const float er2 = g[3];
    const float er1 = er2 * g[2];
    const float er0 = er1 * g[1];
    const float qt  = er0 * g[0];     // product of this quad's 4 keys
    float x = qt;
    float v = __shfl_down(x, 16); x *= (quad < 3) ? v : 1.f;
    v = __shfl_down(x, 32);       x *= (quad < 2) ? v : 1.f;   // inclusive quad-suffix
    float Qs = __shfl_down(x, 16); Qs = (quad < 3) ? Qs : 1.f; // exclusive quad-suffix
    const float tot = __shfl(x, lq);  // full 16-key product (from quad 0, same query)
    const float QF = Qs * cur;
    ushort4 pk;
    pk.x = f2bf(p[0] * (er0 * QF));
    pk.y = f2bf(p[1] * (er1 * QF));
    pk.z = f2bf(p[2] * (er2 * QF));
    pk.w = f2bf(p[3] * QF);
    *(ushort4*)&pw[lq * PSTR + c * 16 + quad * 4] = pk;  // [query][key] row-major
    cur *= tot;
  }
  carry = cur;
  __asm__ volatile("s_waitcnt lgkmcnt(0)" ::: "memory");  // P visible to own wave
  const short8 pA = *(const short8*)&pw[lq * PSTR + quad * 8];       // keys j0+0..31
  const short8 pB = *(const short8*)&pw[lq * PSTR + 32 + quad * 8];  // keys j0+32..63
#pragma unroll
  for (int tt = 0; tt < 4; ++tt) {
    o[tt] = __builtin_amdgcn_mfma_f32_16x16x32_bf16(vfA[tt], pA, o[tt], 0, 0, 0);
    o[tt] = __builtin_amdgcn_mfma_f32_16x16x32_bf16(vfB[tt], pB, o[tt], 0, 0, 0);
  }
  // DS is in-order per wave: next tile's ds_write cannot pass the reads above.
}

__global__ __launch_bounds__(256, 4) void sba_attn(
    const u16* __restrict__ Q, const u16* __restrict__ Km,
    const u16* __restrict__ Vt, u16* __restrict__ AO) {
  __shared__ __align__(16) u16 lP[4][16 * PSTR];
  const int tid = threadIdx.x;
  const int lane = tid & 63;
  const int wave = tid >> 6;
  const int lq = lane & 15, quad = lane >> 4;
  // XCD-affinity swizzle: all 16 blocks of one head land on one XCD (%8 heuristic)
  const int blk = blockIdx.x;
  const int xcd = blk & 7, y = blk >> 3;
  const int bh = xcd + 8 * (y >> 4);
  const int u = (y & 15) * 4 + wave;
  const int t = (u & 1) ? (63 - (u >> 1)) : (u >> 1);  // balance: pair t with 63-t
  const int q0 = t << 4;

  // Q B-frags (pre-scaled by 1/8 in gemm_qkv): B[n=query=lq][k=d]
  const u16* qb = Q + ((size_t)bh * 1024 + q0) * 64;
  const short8 qf0 = *(const short8*)&qb[lq * 64 + quad * 8];
  const short8 qf1 = *(const short8*)&qb[lq * 64 + 32 + quad * 8];

  const u16* kb0 = Km + (size_t)bh * 65536;
  const u16* vb  = Vt + (size_t)bh * 65536;

  floatx4 o[4];
#pragma unroll
  for (int tt = 0; tt < 4; ++tt) o[tt] = (floatx4)0.f;
  float carry = 1.f;
  u16* pw = &lP[wave][0];

  const int j0d = q0 & ~63;  // 64-aligned diagonal tile
  sba_tile<true>(j0d, q0, lq, quad, kb0, vb, pw, qf0, qf1, o, carry);
  for (int j0 = j0d - 64; j0 >= 0; j0 -= 64)
    sba_tile<false>(j0, q0, lq, quad, kb0, vb, pw, qf0, qf1, o, carry);

  // O^T (d=tt*16+quad*4+r, query=lq) -> LDS [query][d] -> coalesced 16B stores
#pragma unroll
  for (int tt = 0; tt < 4; ++tt) {
    ushort4 pk;
    pk.x = f2bf(o[tt][0]); pk.y = f2bf(o[tt][1]);
    pk.z = f2bf(o[tt][2]); pk.w = f2bf(o[tt][3]);
    *(ushort4*)&pw[lq * PSTR + tt * 16 + quad * 4] = pk;
  }
  __asm__ volatile("s_waitcnt lgkmcnt(0)" ::: "memory");
  const int b = bh >> 5, hd = bh & 31;
#pragma unroll
  for (int ps = 0; ps < 2; ++ps) {
    const int row = lane >> 2;
    const int colu = ((lane & 3) + 4 * ps) * 8;
    const short8 val = *(const short8*)&pw[row * PSTR + colu];
    *(short8*)&AO[((size_t)b * 1024 + q0 + row) * 2048 + hd * 64 + colu] = val;
  }
}

extern "C" void kernel_launch(void* const* d_in, const int* in_sizes, int n_in,
                              void* d_out, int out_size, void* d_ws, size_t ws_size,
                              hipStream_t stream) {
  const float* H  = (const float*)d_in[0];
  const float* Wq = (const float*)d_in[1];
  const float* Wk = (const float*)d_in[2];
  const float* Wv = (const float*)d_in[3];
  const float* Wo = (const float*)d_in[4];

  u16* ws = (u16*)d_ws;
  u16* Hb  = ws;                  // [2048,2048] 8MB  (reused as ao after gemm_qkv)
  u16* Wqb = ws + 1 * 4194304;
  u16* Wkb = ws + 2 * 4194304;
  u16* Wvb = ws + 3 * 4194304;
  u16* Wob = ws + 4 * 4194304;
  u16* q   = ws + 5 * 4194304;    // [64,1024,64], pre-scaled by 1/8
  u16* k   = ws + 6 * 4194304;
  u16* vt  = ws + 7 * 4194304;    // [64,64,1024]
  u16* ao  = Hb;                  // alias: H consumed by gemm_qkv before sba_attn writes

  dim3 gc(4096, 5);
  cvt_all<<<gc, 256, 0, stream>>>(H, Wq, Wk, Wv, Wo, ws);

  dim3 gq(16, 48);
  gemm_qkv<<<gq, 256, 0, stream>>>(Hb, Wqb, Wkb, Wvb, q, k, vt);
  sba_attn<<<1024, 256, 0, stream>>>(q, k, vt, ao);
  dim3 go(16, 16);
  gemm_out<<<go, 256, 0, stream>>>(ao, Wob, (float*)d_out);
}